// Round 12
// baseline (359.407 us; speedup 1.0000x reference)
//
#include <hip/hip_runtime.h>

typedef _Float16 f16;
typedef f16    f16x2 __attribute__((ext_vector_type(2)));
typedef f16    f16x8 __attribute__((ext_vector_type(8)));
typedef __fp16 fp16x2 __attribute__((ext_vector_type(2)));
typedef float  f32x4 __attribute__((ext_vector_type(4)));

#define NF 256      // features
#define NH 64       // hidden dim
#define NL 3        // hidden-to-hidden layers
#define NB 4        // 16-row batch tiles per wave -> 64 rows/wave
#define NWAVE 4
#define MT (NB * 16 * NWAVE)   // 256 rows per block
#define NTHR (NWAVE * 64)     // 256
#define WFRAG (NH * NH)

union U2 { f16x8 v8; f16x2 h[4]; };

// sigma(p = 32ks + 8gr + j) = 32ks + 16*(j>>2) + 4gr + (j&3) baked into W
// staging: the MFMA C-tile, packed pairwise, IS the next layer's B-fragment
// (verified r9/r10/r11). h never touches LDS; zero barriers in main kernel.
//
// Numerics (1-term): W rounded once to f16 RTN (2^-11, unbiased); h rounded
// once per layer RTZ via cvt_pkrtz (2^-10). Measured 2-term absmax was
// 0.0039 (h-RTZ only); W-RTN adds incoherently -> expect ~6e-3..1.2e-2,
// threshold 2.1e-2. Fallback if exceeded: restore the r11 2-term kernel.

// pack 2 f32 -> f16x2 with RTZ, then relu in packed f16 (v_pk_max_f16)
__device__ __forceinline__ f16x2 pkmax(float a, float b) {
    fp16x2 p = __builtin_amdgcn_cvt_pkrtz(a, b);
    fp16x2 z = {(__fp16)0.f, (__fp16)0.f};
    p = __builtin_elementwise_max(p, z);
    return __builtin_bit_cast(f16x2, p);
}

// ---- prepass: Wh -> f16 RTN A-fragment plane with sigma baked into k;
// ---- main kernel reads one coalesced f16x8 per lane per (mt,ks).
__global__ __launch_bounds__(256) void presplit_w(
    const float* __restrict__ Wh, f16* __restrict__ wsHi)
{
    __shared__ float wld[NH * NH];
    const int lf = blockIdx.x;            // l*NF + f
    const int t  = threadIdx.x;
    const float* __restrict__ src = Wh + (size_t)lf * WFRAG;
#pragma unroll
    for (int i = 0; i < 4; ++i)
        *(f32x4*)&wld[(i * 256 + t) * 4] = *(const f32x4*)&src[(i * 256 + t) * 4];
    __syncthreads();
#pragma unroll
    for (int g2 = 0; g2 < 2; ++g2) {
        const int g  = g2 * 256 + t;      // g = (mt*2+ks)*64 + ln
        const int ln = g & 63, ks = (g >> 6) & 1, mt = g >> 7;
        const int cl = ln & 15, gr = ln >> 4;
        const int m  = mt * 16 + cl;      // output unit (natural order)
        f16x8 hi;
#pragma unroll
        for (int jj = 0; jj < 8; ++jj) {
            const int u = 32 * ks + 16 * (jj >> 2) + 4 * gr + (jj & 3);  // sigma
            hi[jj] = (f16)wld[u * NH + m];   // RTN
        }
        *(f16x8*)&wsHi[((size_t)lf * 512 + g) * 8] = hi;
    }
}

template <bool PRE>
__global__ __launch_bounds__(NTHR, 6) void permlp_v12(
    const float* __restrict__ x,
    const float* __restrict__ W1,
    const float* __restrict__ b1,
    const float* __restrict__ Wh,
    const float* __restrict__ bh,
    const float* __restrict__ Wo,
    const float* __restrict__ bo,
    const f16* __restrict__ wsHi,
    float* __restrict__ out,
    int nby)
{
    // XCD-chunked bijective swizzle (nwg % 8 == 0): W working set L2-resident.
    const int nwg  = NF * nby;
    const int q    = nwg >> 3;
    const int bid  = blockIdx.x;
    const int wgid = (bid & 7) * q + (bid >> 3);
    const int f    = wgid / nby;
    const int by   = wgid - f * nby;

    const int tid = threadIdx.x;
    const int wv  = tid >> 6;
    const int ln  = tid & 63;
    const int cl  = ln & 15;
    const int gr  = ln >> 4;
    const int gb0 = by * MT + wv * (NB * 16);

    // W fragment loader (one 16x64 tile: 2 x f16x8 per lane)
    auto loadW = [&](const f16* __restrict__ baseH, const float* __restrict__ Wl,
                     int mt, f16x8 (&A)[2]) {
#pragma unroll
        for (int ks = 0; ks < 2; ++ks) {
            if constexpr (PRE) {
                A[ks] = *(const f16x8*)&baseH[(size_t)((mt * 2 + ks) * 64 + ln) * 8];
            } else {
                const int m = mt * 16 + cl;
                f16x8 hi8;
#pragma unroll
                for (int j = 0; j < 8; ++j) {
                    const int u = 32 * ks + 16 * (j >> 2) + 4 * gr + (j & 3);
                    hi8[j] = (f16)Wl[(size_t)u * NH + m];
                }
                A[ks] = hi8;
            }
        }
    };

    // ---- layer 1 straight into registers (sigma-ordered B-fragments) ----
    U2 HA[NB][2], HB[NB][2];
    {
        float xv[NB];
#pragma unroll
        for (int bt = 0; bt < NB; ++bt)
            xv[bt] = x[(size_t)(gb0 + bt * 16 + cl) * NF + f];
        const float* __restrict__ w1 = W1 + f * NH;
        const float* __restrict__ bb = b1 + f * NH;
#pragma unroll
        for (int ks = 0; ks < 2; ++ks)
#pragma unroll
            for (int jq = 0; jq < 2; ++jq) {
                const int ub = 32 * ks + 16 * jq + 4 * gr;   // sigma-ordered
                const f32x4 w4 = *(const f32x4*)&w1[ub];
                const f32x4 b4 = *(const f32x4*)&bb[ub];
#pragma unroll
                for (int bt = 0; bt < NB; ++bt) {
                    float v0 = fmaf(xv[bt], w4[0], b4[0]);
                    float v1 = fmaf(xv[bt], w4[1], b4[1]);
                    float v2 = fmaf(xv[bt], w4[2], b4[2]);
                    float v3 = fmaf(xv[bt], w4[3], b4[3]);
                    HA[bt][ks].h[jq * 2]     = pkmax(v0, v1);   // relu in pk f16
                    HA[bt][ks].h[jq * 2 + 1] = pkmax(v2, v3);
                }
            }
    }

    // ---- one hidden layer: I regs -> O regs, W double-buffered ----
    auto hidden = [&](U2 (&I)[NB][2], U2 (&O)[NB][2], const int l) {
        const f16* __restrict__ baseH = PRE ? wsHi + (size_t)(l * NF + f) * 4096 : nullptr;
        const float* __restrict__ Wl  = Wh + (size_t)(l * NF + f) * WFRAG;
        const float* __restrict__ bl  = bh + (size_t)(l * NF + f) * NH;
        f16x8 WA[2][2];   // [buf][ks]
        loadW(baseH, Wl, 0, WA[0]);
#pragma unroll
        for (int mt = 0; mt < 4; ++mt) {
            if (mt < 3)   // prefetch next tile while this tile computes
                loadW(baseH, Wl, mt + 1, WA[(mt + 1) & 1]);
            const f32x4 bias4 = *(const f32x4*)&bl[mt * 16 + gr * 4];
            f32x4 acc[NB];
#pragma unroll
            for (int bt = 0; bt < NB; ++bt) acc[bt] = bias4;
#pragma unroll
            for (int ks = 0; ks < 2; ++ks)
#pragma unroll
                for (int bt = 0; bt < NB; ++bt)
                    acc[bt] = __builtin_amdgcn_mfma_f32_16x16x32_f16(WA[mt & 1][ks], I[bt][ks].v8, acc[bt], 0, 0, 0);
            // C tile (batch=cl, units mt*16+gr*4+i) -> next-layer fragment
#pragma unroll
            for (int bt = 0; bt < NB; ++bt) {
                O[bt][mt >> 1].h[(mt & 1) * 2]     = pkmax(acc[bt][0], acc[bt][1]);
                O[bt][mt >> 1].h[(mt & 1) * 2 + 1] = pkmax(acc[bt][2], acc[bt][3]);
            }
        }
    };

    hidden(HA, HB, 0);
    hidden(HB, HA, 1);

    // ---- last hidden layer with fused output dot (reads HA) ----
    float souts[NB] = {0.f, 0.f, 0.f, 0.f};
    {
        const int l = NL - 1;
        const f16* __restrict__ baseH = PRE ? wsHi + (size_t)(l * NF + f) * 4096 : nullptr;
        const float* __restrict__ Wl  = Wh + (size_t)(l * NF + f) * WFRAG;
        const float* __restrict__ bl  = bh + (size_t)(l * NF + f) * NH;
        f16x8 WA[2][2];
        loadW(baseH, Wl, 0, WA[0]);
#pragma unroll
        for (int mt = 0; mt < 4; ++mt) {
            if (mt < 3)
                loadW(baseH, Wl, mt + 1, WA[(mt + 1) & 1]);
            const f32x4 bias4 = *(const f32x4*)&bl[mt * 16 + gr * 4];
            f32x4 acc[NB];
#pragma unroll
            for (int bt = 0; bt < NB; ++bt) acc[bt] = bias4;
#pragma unroll
            for (int ks = 0; ks < 2; ++ks)
#pragma unroll
                for (int bt = 0; bt < NB; ++bt)
                    acc[bt] = __builtin_amdgcn_mfma_f32_16x16x32_f16(WA[mt & 1][ks], HA[bt][ks].v8, acc[bt], 0, 0, 0);
            const f32x4 wov4 = *(const f32x4*)&Wo[f * NH + mt * 16 + gr * 4];
#pragma unroll
            for (int bt = 0; bt < NB; ++bt)
#pragma unroll
                for (int i = 0; i < 4; ++i)
                    souts[bt] = fmaf(fmaxf(acc[bt][i], 0.f), wov4[i], souts[bt]);
        }
    }

    // ---- commit: reduce over gr-groups, one atomic per row ----
    const float bof = bo[f];
#pragma unroll
    for (int bt = 0; bt < NB; ++bt) {
        float s = souts[bt];
        s += __shfl_xor(s, 16, 64);
        s += __shfl_xor(s, 32, 64);
        if (ln < 16)
            atomicAdd(&out[gb0 + bt * 16 + ln], s + bof);
    }
}

extern "C" void kernel_launch(void* const* d_in, const int* in_sizes, int n_in,
                              void* d_out, int out_size, void* d_ws, size_t ws_size,
                              hipStream_t stream)
{
    const float* x  = (const float*)d_in[0];
    const float* W1 = (const float*)d_in[1];
    const float* b1 = (const float*)d_in[2];
    const float* Wh = (const float*)d_in[3];
    const float* bh = (const float*)d_in[4];
    const float* Wo = (const float*)d_in[5];
    const float* bo = (const float*)d_in[6];
    float* out = (float*)d_out;

    const int B   = in_sizes[0] / NF;   // 16384
    const int nby = B / MT;             // 64

    hipMemsetAsync(out, 0, (size_t)out_size * sizeof(float), stream);

    const size_t planeElems = (size_t)NL * NF * WFRAG;      // 3.15M f16
    const size_t needW      = planeElems * sizeof(f16);     // ~6.3 MB
    dim3 grid(NF * nby);

    if (ws_size >= needW) {
        f16* wsHi = (f16*)d_ws;
        presplit_w<<<NL * NF, 256, 0, stream>>>(Wh, wsHi);
        permlp_v12<true><<<grid, dim3(NTHR), 0, stream>>>(
            x, W1, b1, Wh, bh, Wo, bo, wsHi, out, nby);
    } else {
        permlp_v12<false><<<grid, dim3(NTHR), 0, stream>>>(
            x, W1, b1, Wh, bh, Wo, bo, nullptr, out, nby);
    }
}

// Round 13
// 139.300 us; speedup vs baseline: 2.5801x; 2.5801x over previous
//
#include <hip/hip_runtime.h>

typedef _Float16 f16;
typedef f16    f16x2 __attribute__((ext_vector_type(2)));
typedef f16    f16x8 __attribute__((ext_vector_type(8)));
typedef __fp16 fp16x2 __attribute__((ext_vector_type(2)));
typedef float  f32x4 __attribute__((ext_vector_type(4)));

#define NF 256      // features
#define NH 64       // hidden dim
#define NL 3        // hidden-to-hidden layers
#define NB 4        // 16-row batch tiles per wave -> 64 rows/wave
#define NWAVE 4
#define MT (NB * 16 * NWAVE)   // 256 rows per block
#define NTHR (NWAVE * 64)     // 256
#define WFRAG (NH * NH)

union U2 { f16x8 v8; f16x2 h[4]; };

// sigma(p = 32ks + 8gr + j) = 32ks + 16*(j>>2) + 4gr + (j&3) baked into W
// staging: the MFMA C-tile, packed pairwise, IS the next layer's B-fragment
// (verified r9-r12). h never touches LDS; zero barriers in the main kernel.
//
// Numerics (1-term): W RTN (2^-11), h RTZ per layer (2^-10). Measured r12
// absmax = 0.0039 (5.4x under threshold) -> 1-term verified safe.
//
// r12 lesson: __launch_bounds__ min-waves=6 capped the unified VGPR/AGPR
// budget at ~85 -> h arrays spilled to scratch (FETCH 667MB, 1.8x slower).
// 4 waves/SIMD (128-reg budget) fits the whole state (r10 precedent).

// pack 2 f32 -> f16x2 with RTZ, then relu in packed f16 (v_pk_max_f16)
__device__ __forceinline__ f16x2 pkmax(float a, float b) {
    fp16x2 p = __builtin_amdgcn_cvt_pkrtz(a, b);
    fp16x2 z = {(__fp16)0.f, (__fp16)0.f};
    p = __builtin_elementwise_max(p, z);
    return __builtin_bit_cast(f16x2, p);
}

// ---- prepass: Wh -> f16 RTN A-fragment plane with sigma baked into k;
// ---- main kernel reads one coalesced f16x8 per lane per (mt,ks).
__global__ __launch_bounds__(256) void presplit_w(
    const float* __restrict__ Wh, f16* __restrict__ wsHi)
{
    __shared__ float wld[NH * NH];
    const int lf = blockIdx.x;            // l*NF + f
    const int t  = threadIdx.x;
    const float* __restrict__ src = Wh + (size_t)lf * WFRAG;
#pragma unroll
    for (int i = 0; i < 4; ++i)
        *(f32x4*)&wld[(i * 256 + t) * 4] = *(const f32x4*)&src[(i * 256 + t) * 4];
    __syncthreads();
#pragma unroll
    for (int g2 = 0; g2 < 2; ++g2) {
        const int g  = g2 * 256 + t;      // g = (mt*2+ks)*64 + ln
        const int ln = g & 63, ks = (g >> 6) & 1, mt = g >> 7;
        const int cl = ln & 15, gr = ln >> 4;
        const int m  = mt * 16 + cl;      // output unit (natural order)
        f16x8 hi;
#pragma unroll
        for (int jj = 0; jj < 8; ++jj) {
            const int u = 32 * ks + 16 * (jj >> 2) + 4 * gr + (jj & 3);  // sigma
            hi[jj] = (f16)wld[u * NH + m];   // RTN
        }
        *(f16x8*)&wsHi[((size_t)lf * 512 + g) * 8] = hi;
    }
}

template <bool PRE>
__global__ __launch_bounds__(NTHR, 4) void permlp_v13(
    const float* __restrict__ x,
    const float* __restrict__ W1,
    const float* __restrict__ b1,
    const float* __restrict__ Wh,
    const float* __restrict__ bh,
    const float* __restrict__ Wo,
    const float* __restrict__ bo,
    const f16* __restrict__ wsHi,
    float* __restrict__ out,
    int nby)
{
    // XCD-chunked bijective swizzle (nwg % 8 == 0): W working set L2-resident.
    const int nwg  = NF * nby;
    const int q    = nwg >> 3;
    const int bid  = blockIdx.x;
    const int wgid = (bid & 7) * q + (bid >> 3);
    const int f    = wgid / nby;
    const int by   = wgid - f * nby;

    const int tid = threadIdx.x;
    const int wv  = tid >> 6;
    const int ln  = tid & 63;
    const int cl  = ln & 15;
    const int gr  = ln >> 4;
    const int gb0 = by * MT + wv * (NB * 16);

    // W fragment loader (one 16x64 tile: 2 x f16x8 per lane)
    auto loadW = [&](const f16* __restrict__ baseH, const float* __restrict__ Wl,
                     int mt, f16x8 (&A)[2]) {
#pragma unroll
        for (int ks = 0; ks < 2; ++ks) {
            if constexpr (PRE) {
                A[ks] = *(const f16x8*)&baseH[(size_t)((mt * 2 + ks) * 64 + ln) * 8];
            } else {
                const int m = mt * 16 + cl;
                f16x8 hi8;
#pragma unroll
                for (int j = 0; j < 8; ++j) {
                    const int u = 32 * ks + 16 * (j >> 2) + 4 * gr + (j & 3);
                    hi8[j] = (f16)Wl[(size_t)u * NH + m];
                }
                A[ks] = hi8;
            }
        }
    };

    // ---- layer 1 straight into registers (sigma-ordered B-fragments) ----
    U2 HA[NB][2], HB[NB][2];
    {
        float xv[NB];
#pragma unroll
        for (int bt = 0; bt < NB; ++bt)
            xv[bt] = x[(size_t)(gb0 + bt * 16 + cl) * NF + f];
        const float* __restrict__ w1 = W1 + f * NH;
        const float* __restrict__ bb = b1 + f * NH;
#pragma unroll
        for (int ks = 0; ks < 2; ++ks)
#pragma unroll
            for (int jq = 0; jq < 2; ++jq) {
                const int ub = 32 * ks + 16 * jq + 4 * gr;   // sigma-ordered
                const f32x4 w4 = *(const f32x4*)&w1[ub];
                const f32x4 b4 = *(const f32x4*)&bb[ub];
#pragma unroll
                for (int bt = 0; bt < NB; ++bt) {
                    float v0 = fmaf(xv[bt], w4[0], b4[0]);
                    float v1 = fmaf(xv[bt], w4[1], b4[1]);
                    float v2 = fmaf(xv[bt], w4[2], b4[2]);
                    float v3 = fmaf(xv[bt], w4[3], b4[3]);
                    HA[bt][ks].h[jq * 2]     = pkmax(v0, v1);   // relu in pk f16
                    HA[bt][ks].h[jq * 2 + 1] = pkmax(v2, v3);
                }
            }
    }

    // ---- one hidden layer: I regs -> O regs, W double-buffered ----
    auto hidden = [&](U2 (&I)[NB][2], U2 (&O)[NB][2], const int l) {
        const f16* __restrict__ baseH = PRE ? wsHi + (size_t)(l * NF + f) * 4096 : nullptr;
        const float* __restrict__ Wl  = Wh + (size_t)(l * NF + f) * WFRAG;
        const float* __restrict__ bl  = bh + (size_t)(l * NF + f) * NH;
        f16x8 WA[2][2];   // [buf][ks]
        loadW(baseH, Wl, 0, WA[0]);
#pragma unroll
        for (int mt = 0; mt < 4; ++mt) {
            if (mt < 3)   // prefetch next tile while this tile computes
                loadW(baseH, Wl, mt + 1, WA[(mt + 1) & 1]);
            const f32x4 bias4 = *(const f32x4*)&bl[mt * 16 + gr * 4];
            f32x4 acc[NB];
#pragma unroll
            for (int bt = 0; bt < NB; ++bt) acc[bt] = bias4;
#pragma unroll
            for (int ks = 0; ks < 2; ++ks)
#pragma unroll
                for (int bt = 0; bt < NB; ++bt)
                    acc[bt] = __builtin_amdgcn_mfma_f32_16x16x32_f16(WA[mt & 1][ks], I[bt][ks].v8, acc[bt], 0, 0, 0);
            // C tile (batch=cl, units mt*16+gr*4+i) -> next-layer fragment
#pragma unroll
            for (int bt = 0; bt < NB; ++bt) {
                O[bt][mt >> 1].h[(mt & 1) * 2]     = pkmax(acc[bt][0], acc[bt][1]);
                O[bt][mt >> 1].h[(mt & 1) * 2 + 1] = pkmax(acc[bt][2], acc[bt][3]);
            }
        }
    };

    hidden(HA, HB, 0);
    hidden(HB, HA, 1);

    // ---- last hidden layer with fused output dot (reads HA) ----
    float souts[NB] = {0.f, 0.f, 0.f, 0.f};
    {
        const int l = NL - 1;
        const f16* __restrict__ baseH = PRE ? wsHi + (size_t)(l * NF + f) * 4096 : nullptr;
        const float* __restrict__ Wl  = Wh + (size_t)(l * NF + f) * WFRAG;
        const float* __restrict__ bl  = bh + (size_t)(l * NF + f) * NH;
        f16x8 WA[2][2];
        loadW(baseH, Wl, 0, WA[0]);
#pragma unroll
        for (int mt = 0; mt < 4; ++mt) {
            if (mt < 3)
                loadW(baseH, Wl, mt + 1, WA[(mt + 1) & 1]);
            const f32x4 bias4 = *(const f32x4*)&bl[mt * 16 + gr * 4];
            f32x4 acc[NB];
#pragma unroll
            for (int bt = 0; bt < NB; ++bt) acc[bt] = bias4;
#pragma unroll
            for (int ks = 0; ks < 2; ++ks)
#pragma unroll
                for (int bt = 0; bt < NB; ++bt)
                    acc[bt] = __builtin_amdgcn_mfma_f32_16x16x32_f16(WA[mt & 1][ks], HA[bt][ks].v8, acc[bt], 0, 0, 0);
            const f32x4 wov4 = *(const f32x4*)&Wo[f * NH + mt * 16 + gr * 4];
#pragma unroll
            for (int bt = 0; bt < NB; ++bt)
#pragma unroll
                for (int i = 0; i < 4; ++i)
                    souts[bt] = fmaf(fmaxf(acc[bt][i], 0.f), wov4[i], souts[bt]);
        }
    }

    // ---- commit: reduce over gr-groups, one atomic per row ----
    const float bof = bo[f];
#pragma unroll
    for (int bt = 0; bt < NB; ++bt) {
        float s = souts[bt];
        s += __shfl_xor(s, 16, 64);
        s += __shfl_xor(s, 32, 64);
        if (ln < 16)
            atomicAdd(&out[gb0 + bt * 16 + ln], s + bof);
    }
}

extern "C" void kernel_launch(void* const* d_in, const int* in_sizes, int n_in,
                              void* d_out, int out_size, void* d_ws, size_t ws_size,
                              hipStream_t stream)
{
    const float* x  = (const float*)d_in[0];
    const float* W1 = (const float*)d_in[1];
    const float* b1 = (const float*)d_in[2];
    const float* Wh = (const float*)d_in[3];
    const float* bh = (const float*)d_in[4];
    const float* Wo = (const float*)d_in[5];
    const float* bo = (const float*)d_in[6];
    float* out = (float*)d_out;

    const int B   = in_sizes[0] / NF;   // 16384
    const int nby = B / MT;             // 64

    hipMemsetAsync(out, 0, (size_t)out_size * sizeof(float), stream);

    const size_t planeElems = (size_t)NL * NF * WFRAG;      // 3.15M f16
    const size_t needW      = planeElems * sizeof(f16);     // ~6.3 MB
    dim3 grid(NF * nby);

    if (ws_size >= needW) {
        f16* wsHi = (f16*)d_ws;
        presplit_w<<<NL * NF, 256, 0, stream>>>(Wh, wsHi);
        permlp_v13<true><<<grid, dim3(NTHR), 0, stream>>>(
            x, W1, b1, Wh, bh, Wo, bo, wsHi, out, nby);
    } else {
        permlp_v13<false><<<grid, dim3(NTHR), 0, stream>>>(
            x, W1, b1, Wh, bh, Wo, bo, nullptr, out, nby);
    }
}